// Round 2
// baseline (3301.341 us; speedup 1.0000x reference)
//
#include <hip/hip_runtime.h>

// GRU + linear readout, B=128 T=2048 IN=32 H=256 L=16
// One block per batch row (128 blocks, 8 waves). Whh (f16) k-tiles 0..6 in
// VGPRs (168/lane), k-tile 7 in LDS (chunk-major, conflict-free). Per step:
// hg = [1x256]x[256x768] via mfma_f32_16x16x32_f16 with all A-rows broadcast-
// identical (batch dim padded 1->16); x-side gates fused as MFMA accumulator
// seed (r,z) or separate LDS buffer (n-gate); elementwise gates on tid<256.

typedef _Float16 half8 __attribute__((ext_vector_type(8)));
typedef float float4v __attribute__((ext_vector_type(4)));

#define TT 2048
#define LOG2E 1.44269504088896f

__device__ __forceinline__ float sigm(float x) {
    return __builtin_amdgcn_rcpf(1.f + __builtin_amdgcn_exp2f(-LOG2E * x));
}
__device__ __forceinline__ float tanhf_(float x) {
    float e = __builtin_amdgcn_exp2f(2.f * LOG2E * x);   // inf-safe: ->1 / ->-1
    return 1.f - 2.f * __builtin_amdgcn_rcpf(e + 1.f);
}

// dynamic LDS layout (bytes):
//   [0, 49152)        Whh k-tile 7 (k=224..255) f16, chunk-major:
//                     byte = qc*12288 + row*16  (qc = k-chunk 0..3, row 0..767)
//   [49152, 52224)    lds_hg : 768 f32 (h-side gate preacts; r,z incl. x-side)
//   [52224, 53248)    lds_ig : 256 f32 (x-side n-gate preact)
//   [53248, 53760)    lds_h  : 256 f16 (hidden state)
//   [53760, 53824)    lds_x  : 32  f16 (current x_t)
#define OFF_HG 49152
#define OFF_IG 52224
#define OFF_H  53248
#define OFF_X  53760
#define SMEM_BYTES 53824

__launch_bounds__(512, 2)
__global__ void gru_kernel(const float* __restrict__ xg,    // [B,T,32]
                           const float* __restrict__ xlin,  // [B,T,16]
                           const float* __restrict__ h0,    // [B,256]
                           const float* __restrict__ Wih,   // [768,32]
                           const float* __restrict__ Whh,   // [768,256]
                           const float* __restrict__ bias,  // [768]
                           const float* __restrict__ biasn, // [256]
                           float* __restrict__ out)         // [B*T]
{
    extern __shared__ char smem[];
    _Float16* ldsW  = (_Float16*)smem;
    float*    ldsHG = (float*)(smem + OFF_HG);
    float*    ldsIG = (float*)(smem + OFF_IG);
    _Float16* ldsH  = (_Float16*)(smem + OFF_H);
    _Float16* ldsX  = (_Float16*)(smem + OFF_X);

    const int b    = blockIdx.x;
    const int tid  = threadIdx.x;
    const int lane = tid & 63;
    const int w    = tid >> 6;      // wave 0..7
    const int l15  = lane & 15;
    const int lhi  = lane >> 4;     // 0..3
    const int n0   = w * 96;        // this wave's first output column

    // ---- Whh k-tiles 0..6 and Wih fragments into registers (f16 RTN)
    half8 Wh[6][7];
    half8 Wx[6];
#pragma unroll
    for (int nt = 0; nt < 6; ++nt) {
        int row = n0 + nt * 16 + l15;
#pragma unroll
        for (int kt = 0; kt < 7; ++kt) {
            const float4v* p = (const float4v*)(Whh + row * 256 + kt * 32 + lhi * 8);
            float4v u = p[0], v2 = p[1];
            half8 v;
#pragma unroll
            for (int j = 0; j < 4; ++j) { v[j] = (_Float16)u[j]; v[4 + j] = (_Float16)v2[j]; }
            Wh[nt][kt] = v;
        }
        const float4v* q = (const float4v*)(Wih + row * 32 + lhi * 8);
        float4v u = q[0], v2 = q[1];
        half8 vx;
#pragma unroll
        for (int j = 0; j < 4; ++j) { vx[j] = (_Float16)u[j]; vx[4 + j] = (_Float16)v2[j]; }
        Wx[nt] = vx;
    }

    // ---- stage Whh k-tile 7 (k=224..255) into LDS, chunk-major, full cover
    for (int c = tid; c < 3072; c += 512) {      // 768 rows * 4 chunks
        int n  = c >> 2;
        int qc = c & 3;
        const float* p = Whh + n * 256 + 224 + qc * 8;
        half8 v;
#pragma unroll
        for (int j = 0; j < 8; ++j) v[j] = (_Float16)p[j];
        *(half8*)((char*)ldsW + qc * 12288 + n * 16) = v;
    }

    // ---- init hidden state, x0, biases
    float hreg = 0.f, b_r = 0.f, b_z = 0.f, b_in = 0.f, b_hn = 0.f;
    if (tid < 256) {
        hreg = h0[b * 256 + tid];
        ldsH[tid] = (_Float16)hreg;
        b_r  = bias[tid];
        b_z  = bias[tid + 256];
        b_in = bias[tid + 512];
        b_hn = biasn[tid];
    }
    if (tid < 32) ldsX[tid] = (_Float16)xg[(size_t)b * TT * 32 + tid];
    float xlcur = 0.f;
    if (w == 0 && lane < 16) xlcur = xlin[(size_t)b * TT * 16 + lane];
    __syncthreads();

    // per-nt byte offsets into the LDS weight slice (chunk-major)
    int wboff[6];
#pragma unroll
    for (int nt = 0; nt < 6; ++nt)
        wboff[nt] = lhi * 12288 + (n0 + nt * 16 + l15) * 16;

    const float4v zero4 = {0.f, 0.f, 0.f, 0.f};

#pragma clang loop unroll(disable)
    for (int t = 0; t < TT; ++t) {
        int tn = (t < TT - 1) ? t + 1 : TT - 1;
        // prefetch next-step inputs (latency hidden under MFMA phase)
        float xlnext = 0.f, xnext = 0.f;
        if (w == 0 && lane < 16) xlnext = xlin[((size_t)b * TT + tn) * 16 + lane];
        if (w == 4 && lane < 32) xnext  = xg[((size_t)b * TT + tn) * 32 + lane];

        // ---- phase 1: MFMAs
        half8 ax = ((half8*)ldsX)[lhi];
        float4v acc[6];
#pragma unroll
        for (int nt = 0; nt < 6; ++nt) {
            float4v xq = __builtin_amdgcn_mfma_f32_16x16x32_f16(ax, Wx[nt], zero4, 0, 0, 0);
            int gt = w * 6 + nt;                 // global 16-col tile (0..47)
            if (gt >= 32) {                      // n-gate tile: keep x-part separate
                if (lane < 16) ldsIG[gt * 16 + lane - 512] = xq[0];
                acc[nt] = zero4;
            } else {                             // r/z tile: seed accumulator
                acc[nt] = xq;
            }
        }
#pragma unroll
        for (int kt = 0; kt < 8; ++kt) {
            half8 a = ((half8*)ldsH)[kt * 4 + lhi];   // broadcast h fragment
#pragma unroll
            for (int nt = 0; nt < 6; ++nt) {
                half8 bb;
                if (kt < 7) bb = Wh[nt][kt];
                else        bb = *(const half8*)((const char*)ldsW + wboff[nt]);
                acc[nt] = __builtin_amdgcn_mfma_f32_16x16x32_f16(a, bb, acc[nt], 0, 0, 0);
            }
        }
#pragma unroll
        for (int nt = 0; nt < 6; ++nt)
            if (lane < 16) ldsHG[w * 96 + nt * 16 + lane] = acc[nt][0];

        __syncthreads();   // B1: gate preacts visible

        // ---- phase 2: elementwise gates + state update + readout
        if (tid < 256) {
            float g_r = ldsHG[tid] + b_r;            // ir + hr + bias_r
            float g_z = ldsHG[tid + 256] + b_z;      // iz + hz + bias_z
            float hn  = ldsHG[tid + 512];            // h-side n preact
            float inw = ldsIG[tid] + b_in;           // x-side n preact + bias
            float r = sigm(g_r);
            float z = sigm(g_z);
            float n = tanhf_(inw + r * (hn + b_hn));
            float hnew = n + z * (hreg - n);
            hreg = hnew;
            ldsH[tid] = (_Float16)hnew;
            if (tid < 16) {
                float v = hnew * xlcur;
                v += __shfl_xor(v, 8);
                v += __shfl_xor(v, 4);
                v += __shfl_xor(v, 2);
                v += __shfl_xor(v, 1);
                if (tid == 0) out[(size_t)b * TT + t] = v;
            }
        }
        if (w == 4 && lane < 32) ldsX[lane] = (_Float16)xnext;  // stage x_{t+1}
        xlcur = xlnext;
        __syncthreads();   // B2: new h / new x visible
    }
}

extern "C" void kernel_launch(void* const* d_in, const int* in_sizes, int n_in,
                              void* d_out, int out_size, void* d_ws, size_t ws_size,
                              hipStream_t stream) {
    const float* xg    = (const float*)d_in[0];
    const float* xlin  = (const float*)d_in[1];
    const float* h0    = (const float*)d_in[2];
    const float* Wih   = (const float*)d_in[3];
    const float* Whh   = (const float*)d_in[4];
    const float* bias  = (const float*)d_in[5];
    const float* biasn = (const float*)d_in[6];
    float* out = (float*)d_out;

    gru_kernel<<<128, 512, SMEM_BYTES, stream>>>(xg, xlin, h0, Wih, Whh, bias, biasn, out);
}

// Round 3
// 2920.650 us; speedup vs baseline: 1.1303x; 1.1303x over previous
//
#include <hip/hip_runtime.h>

// GRU + linear readout, B=128 T=2048 IN=32 H=256 L=16.
// One block per batch row (128 blocks, 8 waves of 64). Whh as f16: k-tiles
// 0..6 in VGPRs (168/lane), k-tile 7 in LDS (chunk-major, conflict-free).
// Wave w owns output tiles {2w,2w+1} (r), {2w+16,2w+17} (z), {2w+32,2w+33}
// (n) -> gate math is wave-local from MFMA accumulators; ONE barrier/step.
// h exchanged via double-buffered LDS (2x256 f16). x_t fragment prefetched
// into registers (broadcast load), no LDS staging.

typedef _Float16 half8 __attribute__((ext_vector_type(8)));
typedef float float4v __attribute__((ext_vector_type(4)));

#define TT 2048
#define LOG2E 1.44269504088896f

__device__ __forceinline__ float sigm(float x) {
    return __builtin_amdgcn_rcpf(1.f + __builtin_amdgcn_exp2f(-LOG2E * x));
}
__device__ __forceinline__ float tanhf_(float x) {
    float e = __builtin_amdgcn_exp2f(2.f * LOG2E * x);   // inf-safe: ->1 / ->-1
    return 1.f - 2.f * __builtin_amdgcn_rcpf(e + 1.f);
}

__launch_bounds__(512)
__global__ void gru_kernel(const float* __restrict__ xg,    // [B,T,32]
                           const float* __restrict__ xlin,  // [B,T,16]
                           const float* __restrict__ h0,    // [B,256]
                           const float* __restrict__ Wih,   // [768,32]
                           const float* __restrict__ Whh,   // [768,256]
                           const float* __restrict__ bias,  // [768]
                           const float* __restrict__ biasn, // [256]
                           float* __restrict__ out)         // [B*T]
{
    __shared__ _Float16 ldsW[24576];     // 49152 B: Whh k-tile 7, chunk-major
                                         // byte = qc*12288 + row*16
    __shared__ _Float16 ldsH[2][256];    // double-buffered hidden state

    const int tid  = threadIdx.x;
    const int b    = blockIdx.x;
    const int lane = tid & 63;
    const int w    = tid >> 6;      // wave 0..7
    const int l15  = lane & 15;
    const int lhi  = lane >> 4;     // 0..3 (k-chunk)

    // ---- Whh k-tiles 0..6 + Wih fragments into registers (f16 RTN)
    half8 Wh[6][7], Wx[6];
#pragma unroll
    for (int nt = 0; nt < 6; ++nt) {
        const int gtile = 2 * w + (nt >> 1) * 16 + (nt & 1);  // {2w,2w+1,2w+16,2w+17,2w+32,2w+33}
        const int row = gtile * 16 + l15;
#pragma unroll
        for (int kt = 0; kt < 7; ++kt) {
            const float4v* pp = (const float4v*)(Whh + row * 256 + kt * 32 + lhi * 8);
            float4v u = pp[0], v2 = pp[1];
            half8 hv;
#pragma unroll
            for (int j = 0; j < 4; ++j) { hv[j] = (_Float16)u[j]; hv[4 + j] = (_Float16)v2[j]; }
            Wh[nt][kt] = hv;
        }
        const float4v* qq = (const float4v*)(Wih + row * 32 + lhi * 8);
        float4v u = qq[0], v2 = qq[1];
        half8 hv;
#pragma unroll
        for (int j = 0; j < 4; ++j) { hv[j] = (_Float16)u[j]; hv[4 + j] = (_Float16)v2[j]; }
        Wx[nt] = hv;
    }

    // ---- stage Whh k-tile 7 (k=224..255) into LDS, chunk-major, full cover
    for (int c = tid; c < 3072; c += 512) {      // 768 rows * 4 chunks
        int n  = c >> 2;
        int qc = c & 3;
        const float* p = Whh + n * 256 + 224 + qc * 8;
        half8 v;
#pragma unroll
        for (int j = 0; j < 8; ++j) v[j] = (_Float16)p[j];
        *(half8*)((char*)ldsW + qc * 12288 + n * 16) = v;
    }

    // ---- biases + hidden state for this wave's 2 column groups
    float br[2], bz[2], bi[2], bn2[2], hreg[2];
#pragma unroll
    for (int q = 0; q < 2; ++q) {
        const int c = w * 32 + q * 16 + l15;
        br[q]  = bias[c];
        bz[q]  = bias[256 + c];
        bi[q]  = bias[512 + c];
        bn2[q] = biasn[c];
        hreg[q] = h0[b * 256 + c];
    }
    if (tid < 256) ldsH[0][tid] = (_Float16)h0[b * 256 + tid];

    // ---- x_0 fragment into registers
    const float* xgb = xg + (size_t)b * TT * 32;
    half8 ax;
    {
        const float4v* px = (const float4v*)(xgb + lhi * 8);
        float4v u = px[0], v2 = px[1];
#pragma unroll
        for (int j = 0; j < 4; ++j) { ax[j] = (_Float16)u[j]; ax[4 + j] = (_Float16)v2[j]; }
    }
    float xlc = 0.f;
    if (w == 0 && lane < 16) xlc = xlin[(size_t)b * TT * 16 + lane];

    __syncthreads();

    const int wb = lhi * 12288 + l15 * 16 + w * 512;   // LDS weight base (+gt*256 per tile)
    const float4v zero4 = {0.f, 0.f, 0.f, 0.f};

#pragma clang loop unroll(disable)
    for (int t = 0; t < TT; ++t) {
        const int p  = t & 1;
        const int tn = (t < TT - 1) ? t + 1 : t;

        // prefetch next-step inputs into registers (latency hidden under MFMAs)
        const float4v* px = (const float4v*)(xgb + (size_t)tn * 32 + lhi * 8);
        float4v xa = px[0], xb2 = px[1];
        float xln = 0.f;
        if (w == 0 && lane < 16) xln = xlin[((size_t)b * TT + tn) * 16 + lane];

        // ---- x-side MFMAs (K=32=IN): seed r/z accs, keep n-gate x-part separate
        float4v acc[6];
        float xn[2];
#pragma unroll
        for (int nt = 0; nt < 6; ++nt) {
            float4v xq = __builtin_amdgcn_mfma_f32_16x16x32_f16(ax, Wx[nt], zero4, 0, 0, 0);
            if (nt >= 4) { xn[nt - 4] = xq[0]; acc[nt] = zero4; }
            else         { acc[nt] = xq; }
        }
        // ---- h-side MFMAs over 8 k-tiles
#pragma unroll
        for (int kt = 0; kt < 8; ++kt) {
            half8 a = ((const half8*)ldsH[p])[kt * 4 + lhi];   // broadcast h fragment
#pragma unroll
            for (int nt = 0; nt < 6; ++nt) {
                half8 bb;
                if (kt < 7) {
                    bb = Wh[nt][kt];
                } else {
                    const int gtile = 2 * w + (nt >> 1) * 16 + (nt & 1);
                    bb = *(const half8*)((const char*)ldsW + wb + (gtile - 2 * w) * 256);
                    (void)gtile;
                }
                acc[nt] = __builtin_amdgcn_mfma_f32_16x16x32_f16(a, bb, acc[nt], 0, 0, 0);
            }
        }

        // ---- gates: wave-local, straight from accumulators (row 0 on all lanes)
#pragma unroll
        for (int q = 0; q < 2; ++q) {
            float r = sigm(acc[q][0] + br[q]);
            float z = sigm(acc[2 + q][0] + bz[q]);
            float n = tanhf_(xn[q] + bi[q] + r * (acc[4 + q][0] + bn2[q]));
            float hnew = n + z * (hreg[q] - n);
            hreg[q] = hnew;
            if (lane < 16) ldsH[p ^ 1][w * 32 + q * 16 + l15] = (_Float16)hnew;
        }

        // ---- readout: cols 0..15 live in wave 0 (tile 0)
        if (w == 0) {
            float v = hreg[0] * xlc;
            v += __shfl_xor(v, 8, 16);
            v += __shfl_xor(v, 4, 16);
            v += __shfl_xor(v, 2, 16);
            v += __shfl_xor(v, 1, 16);
            if (lane == 0) out[(size_t)b * TT + t] = v;
        }

        // ---- commit prefetched x for next step
#pragma unroll
        for (int j = 0; j < 4; ++j) { ax[j] = (_Float16)xa[j]; ax[4 + j] = (_Float16)xb2[j]; }
        xlc = xln;
        __syncthreads();   // new h visible; old h-buffer free for next write
    }
}

extern "C" void kernel_launch(void* const* d_in, const int* in_sizes, int n_in,
                              void* d_out, int out_size, void* d_ws, size_t ws_size,
                              hipStream_t stream) {
    const float* xg    = (const float*)d_in[0];
    const float* xlin  = (const float*)d_in[1];
    const float* h0    = (const float*)d_in[2];
    const float* Wih   = (const float*)d_in[3];
    const float* Whh   = (const float*)d_in[4];
    const float* bias  = (const float*)d_in[5];
    const float* biasn = (const float*)d_in[6];
    float* out = (float*)d_out;

    gru_kernel<<<128, 512, 0, stream>>>(xg, xlin, h0, Wih, Whh, bias, biasn, out);
}